// Round 1
// baseline (12669.614 us; speedup 1.0000x reference)
//
#include <hip/hip_runtime.h>
#include <math.h>

// Problem constants (fixed by the reference)
#define NP    100000      // primal nodes
#define EP    1600000     // primal edges
#define NDU   1600000     // dual nodes
#define EDU   3200000     // dual edges
#define FIN   512
#define NHEAD 8
#define HIDC  8
#define NCLS  16
#define NEGS  0.2f
#define TPB   256

static __device__ __forceinline__ float lrelu(float x){ return x > 0.f ? x : NEGS*x; }

// ===================== dual (line-graph) GCN branch =====================
// GCN reformulated: out[d] = dinv[d] * ( sum_{e: s->d} dinv[s]*h[s] + dinv[d]*h[d] ) + b
// (self-loop term folded into the finalize pass; h prescaled by dinv once per node)

__global__ void k_deg(const int* __restrict__ dd, float* __restrict__ deg){
  int e = blockIdx.x*TPB + threadIdx.x;
  if(e < EDU) atomicAdd(deg + dd[e], 1.0f);
}

__global__ void k_dinv(float* __restrict__ dinv){
  int i = blockIdx.x*TPB + threadIdx.x;
  if(i < NDU) dinv[i] = rsqrtf(dinv[i] + 1.0f);   // +1 = self loop; always >= 1
}

// A[n][j] = dinv[n] * sum_k x[n][k]*Wg1[k][j]   (Wg1: [4][8])
__global__ void k_dh1(const float* __restrict__ x, const float* __restrict__ Wg1,
                      const float* __restrict__ dinv, float* __restrict__ A){
  int n = blockIdx.x*TPB + threadIdx.x;
  if(n >= NDU) return;
  const float4 xv = *(const float4*)(x + n*4);
  const float dv = dinv[n];
  float o[8];
  #pragma unroll
  for(int j=0;j<8;j++)
    o[j] = dv*(xv.x*Wg1[j] + xv.y*Wg1[8+j] + xv.z*Wg1[16+j] + xv.w*Wg1[24+j]);
  *(float4*)(A + n*8)     = make_float4(o[0],o[1],o[2],o[3]);
  *(float4*)(A + n*8 + 4) = make_float4(o[4],o[5],o[6],o[7]);
}

__global__ void k_dscat1(const int* __restrict__ ds, const int* __restrict__ dd,
                         const float* __restrict__ A, float* __restrict__ B){
  int e = blockIdx.x*TPB + threadIdx.x;
  if(e >= EDU) return;
  int s = ds[e], d = dd[e];
  float4 a0 = *(const float4*)(A + s*8);
  float4 a1 = *(const float4*)(A + s*8 + 4);
  float* b = B + d*8;
  atomicAdd(b+0, a0.x); atomicAdd(b+1, a0.y); atomicAdd(b+2, a0.z); atomicAdd(b+3, a0.w);
  atomicAdd(b+4, a1.x); atomicAdd(b+5, a1.y); atomicAdd(b+6, a1.z); atomicAdd(b+7, a1.w);
}

// Q1[n][j] = relu(dinv[n]*(acc + A[n][j]) + bg1[j])   (in place in B)
__global__ void k_q1fin(const float* __restrict__ A, float* __restrict__ B,
                        const float* __restrict__ dinv, const float* __restrict__ bg1){
  int n = blockIdx.x*TPB + threadIdx.x;
  if(n >= NDU) return;
  float dv = dinv[n];
  float o[8];
  #pragma unroll
  for(int j=0;j<8;j++){
    float v = dv*(B[n*8+j] + A[n*8+j]) + bg1[j];
    o[j] = v > 0.f ? v : 0.f;
  }
  *(float4*)(B + n*8)     = make_float4(o[0],o[1],o[2],o[3]);
  *(float4*)(B + n*8 + 4) = make_float4(o[4],o[5],o[6],o[7]);
}

// A2[n][c] = dinv[n] * sum_k Q1[n][k]*Wg2[k][c]   (Wg2: [8][16])
__global__ void k_dh2(const float* __restrict__ Q1, const float* __restrict__ Wg2,
                      const float* __restrict__ dinv, float* __restrict__ A){
  int n = blockIdx.x*TPB + threadIdx.x;
  if(n >= NDU) return;
  float q[8];
  *(float4*)(q)   = *(const float4*)(Q1 + n*8);
  *(float4*)(q+4) = *(const float4*)(Q1 + n*8 + 4);
  float dv = dinv[n];
  float o[16];
  #pragma unroll
  for(int c=0;c<16;c++){
    float acc = 0.f;
    #pragma unroll
    for(int k=0;k<8;k++) acc += q[k]*Wg2[k*16+c];
    o[c] = dv*acc;
  }
  #pragma unroll
  for(int c4=0;c4<16;c4+=4)
    *(float4*)(A + n*16 + c4) = make_float4(o[c4],o[c4+1],o[c4+2],o[c4+3]);
}

__global__ void k_dscat2(const int* __restrict__ ds, const int* __restrict__ dd,
                         const float* __restrict__ A, float* __restrict__ Qo){
  int e = blockIdx.x*TPB + threadIdx.x;
  if(e >= EDU) return;
  int s = ds[e], d = dd[e];
  const float* a = A + s*16;
  float* qo = Qo + d*16;
  #pragma unroll
  for(int c=0;c<16;c++) atomicAdd(qo + c, a[c]);
}

__global__ void k_qfin(const float* __restrict__ A, float* __restrict__ Qo,
                       const float* __restrict__ dinv, const float* __restrict__ bg2){
  int n = blockIdx.x*TPB + threadIdx.x;
  if(n >= NDU) return;
  float dv = dinv[n];
  #pragma unroll
  for(int c=0;c<16;c++)
    Qo[n*16+c] = dv*(Qo[n*16+c] + A[n*16+c]) + bg2[c];
}

// ===================== primal GAT branch =====================

// H = x @ W1 : [100000,512]x[512,64]. 16 rows/block staged in LDS, W1 from L2.
__global__ __launch_bounds__(TPB) void k_gemm1(const float* __restrict__ x,
                                               const float* __restrict__ W,
                                               float* __restrict__ H){
  __shared__ float xs[16][FIN+4];   // +4 pad: rq-broadcast reads hit distinct banks
  const int r0 = blockIdx.x*16;     // NP % 16 == 0, no guards needed
  for(int i=threadIdx.x; i<16*(FIN/4); i+=TPB){
    int r = i >> 7;               // FIN/4 = 128
    int k4 = (i & 127)*4;
    float4 v = *(const float4*)(x + (r0+r)*FIN + k4);
    xs[r][k4+0]=v.x; xs[r][k4+1]=v.y; xs[r][k4+2]=v.z; xs[r][k4+3]=v.w;
  }
  __syncthreads();
  const int c4 = (threadIdx.x & 15)*4;   // 4 cols per thread
  const int rq = threadIdx.x >> 4;       // 1 row per thread (16 rows)
  float a0=0.f,a1=0.f,a2=0.f,a3=0.f;
  #pragma unroll 8
  for(int k=0;k<FIN;k++){
    float xv = xs[rq][k];
    float4 wv = *(const float4*)(W + k*64 + c4);
    a0 += xv*wv.x; a1 += xv*wv.y; a2 += xv*wv.z; a3 += xv*wv.w;
  }
  *(float4*)(H + (r0+rq)*64 + c4) = make_float4(a0,a1,a2,a3);
}

// als[n,h] = sum_c H[n,h,c]*att_src[h,c];  ald likewise
__global__ void k_alpha(const float* __restrict__ H, const float* __restrict__ aw_s,
                        const float* __restrict__ aw_d,
                        float* __restrict__ als, float* __restrict__ ald){
  int i = blockIdx.x*TPB + threadIdx.x;     // over NP*8
  if(i >= NP*NHEAD) return;
  int n = i >> 3, h = i & 7;
  const float* hp = H + n*64 + h*8;
  float s = 0.f, d = 0.f;
  #pragma unroll
  for(int c=0;c<8;c++){ float v = hp[c]; s += v*aw_s[h*8+c]; d += v*aw_d[h*8+c]; }
  als[i] = s; ald[i] = d;
}

// denominator pass (segment_max skipped: |logit| <~ 7, exp() safe in fp32, and
// exp(e)/sum exp(e) == exp(e-m)/sum exp(e-m) mathematically)
__global__ void k_den1(const int* __restrict__ es, const int* __restrict__ ed,
                       const float* __restrict__ als, const float* __restrict__ ald,
                       float* __restrict__ den){
  int e = blockIdx.x*TPB + threadIdx.x;
  if(e >= EP+NP) return;
  int s, d;
  if(e < EP){ s = es[e]; d = ed[e]; } else { s = e - EP; d = s; }   // implicit self loops
  const float* as_ = als + s*8;
  const float* ad_ = ald + d*8;
  float* dn = den + d*8;
  #pragma unroll
  for(int h=0;h<8;h++) atomicAdd(dn + h, __expf(lrelu(as_[h] + ad_[h])));
}

__global__ void k_agg1(const int* __restrict__ es, const int* __restrict__ ed,
                       const float* __restrict__ als, const float* __restrict__ ald,
                       const float* __restrict__ den, const float* __restrict__ H,
                       float* __restrict__ O){
  int e = blockIdx.x*TPB + threadIdx.x;
  if(e >= EP+NP) return;
  int s, d;
  if(e < EP){ s = es[e]; d = ed[e]; } else { s = e - EP; d = s; }
  const float* as_ = als + s*8;
  const float* ad_ = ald + d*8;
  const float* dn  = den + d*8;
  const float* hs  = H + s*64;
  float* od = O + d*64;
  #pragma unroll
  for(int h=0;h<8;h++){
    float w = __expf(lrelu(as_[h] + ad_[h])) / (dn[h] + 1e-16f);
    float4 v0 = *(const float4*)(hs + h*8);
    float4 v1 = *(const float4*)(hs + h*8 + 4);
    atomicAdd(od+h*8+0, w*v0.x); atomicAdd(od+h*8+1, w*v0.y);
    atomicAdd(od+h*8+2, w*v0.z); atomicAdd(od+h*8+3, w*v0.w);
    atomicAdd(od+h*8+4, w*v1.x); atomicAdd(od+h*8+5, w*v1.y);
    atomicAdd(od+h*8+6, w*v1.z); atomicAdd(od+h*8+7, w*v1.w);
  }
}

__global__ void k_elu(float* __restrict__ O, const float* __restrict__ b1){
  int i = blockIdx.x*TPB + threadIdx.x;
  if(i >= NP*64) return;
  float v = O[i] + b1[i & 63];
  O[i] = v > 0.f ? v : expm1f(v);
}

// G = h2 @ W2 ([64][16]) + attention logits for layer 2 (heads=1)
__global__ void k_g(const float* __restrict__ O, const float* __restrict__ W2,
                    const float* __restrict__ asw, const float* __restrict__ adw,
                    float* __restrict__ G, float* __restrict__ as2, float* __restrict__ ad2){
  __shared__ float w2s[64*NCLS];
  for(int i=threadIdx.x; i<64*NCLS; i+=TPB) w2s[i] = W2[i];
  __syncthreads();
  int n = blockIdx.x*TPB + threadIdx.x;
  if(n >= NP) return;
  float g[16];
  #pragma unroll
  for(int c=0;c<16;c++) g[c] = 0.f;
  const float* op = O + n*64;
  #pragma unroll
  for(int k4=0;k4<64;k4+=4){
    float4 v = *(const float4*)(op + k4);
    #pragma unroll
    for(int c=0;c<16;c++){
      g[c] += v.x*w2s[(k4+0)*16+c] + v.y*w2s[(k4+1)*16+c]
            + v.z*w2s[(k4+2)*16+c] + v.w*w2s[(k4+3)*16+c];
    }
  }
  float s=0.f, t=0.f;
  #pragma unroll
  for(int c=0;c<16;c++){ s += g[c]*asw[c]; t += g[c]*adw[c]; }
  #pragma unroll
  for(int c4=0;c4<16;c4+=4)
    *(float4*)(G + n*16 + c4) = make_float4(g[c4],g[c4+1],g[c4+2],g[c4+3]);
  as2[n] = s; ad2[n] = t;
}

__global__ void k_den2(const int* __restrict__ es, const int* __restrict__ ed,
                       const float* __restrict__ as2, const float* __restrict__ ad2,
                       float* __restrict__ den2){
  int e = blockIdx.x*TPB + threadIdx.x;
  if(e >= EP+NP) return;
  int s, d;
  if(e < EP){ s = es[e]; d = ed[e]; } else { s = e - EP; d = s; }
  atomicAdd(den2 + d, __expf(lrelu(as2[s] + ad2[d])));
}

__global__ void k_outinit(float* __restrict__ out, const float* __restrict__ b2){
  int i = blockIdx.x*TPB + threadIdx.x;
  if(i < NP*16) out[i] = b2[i & 15];
}

__global__ void k_agg2(const int* __restrict__ es, const int* __restrict__ ed,
                       const float* __restrict__ as2, const float* __restrict__ ad2,
                       const float* __restrict__ den2, const float* __restrict__ G,
                       float* __restrict__ out){
  int e = blockIdx.x*TPB + threadIdx.x;
  if(e >= EP+NP) return;
  int s, d;
  if(e < EP){ s = es[e]; d = ed[e]; } else { s = e - EP; d = s; }
  float w = __expf(lrelu(as2[s] + ad2[d])) / (den2[d] + 1e-16f);
  const float* gs = G + s*16;
  float* od = out + d*16;
  #pragma unroll
  for(int c=0;c<16;c++) atomicAdd(od + c, w*gs[c]);
}

// ===================== launch =====================

extern "C" void kernel_launch(void* const* d_in, const int* in_sizes, int n_in,
                              void* d_out, int out_size, void* d_ws, size_t ws_size,
                              hipStream_t stream){
  const float* x    = (const float*)d_in[0];
  const int*   ei   = (const int*)  d_in[1];
  const float* dx   = (const float*)d_in[2];
  const int*   dei  = (const int*)  d_in[3];
  const float* W1   = (const float*)d_in[4];
  const float* aw1s = (const float*)d_in[5];
  const float* aw1d = (const float*)d_in[6];
  const float* b1   = (const float*)d_in[7];
  const float* W2   = (const float*)d_in[8];
  const float* aw2s = (const float*)d_in[9];
  const float* aw2d = (const float*)d_in[10];
  const float* b2   = (const float*)d_in[11];
  const float* Wg1  = (const float*)d_in[12];
  const float* bg1  = (const float*)d_in[13];
  const float* Wg2  = (const float*)d_in[14];
  const float* bg2  = (const float*)d_in[15];

  float* out = (float*)d_out;          // [NP,16]
  float* Qo  = out + NP*NCLS;          // [NDU,16]

  // workspace layout (floats): dinv[1.6M] | A[25.6M] | B[12.8M]  = 160 MB
  float* ws   = (float*)d_ws;
  float* dinv = ws;
  float* A    = ws + 1600000;
  float* B    = A  + 25600000;
  // primal overlays in A (dual branch fully done before primal starts)
  float* H1   = A;                 // 6.4M
  float* O1   = A + 6400000;       // 6.4M
  float* G    = A + 12800000;      // 1.6M
  float* als  = A + 14400000;      // 0.8M
  float* ald  = A + 15200000;      // 0.8M
  float* den1 = A + 16000000;      // 0.8M
  float* as2  = A + 16800000;      // 0.1M
  float* ad2  = A + 16900000;      // 0.1M
  float* den2 = A + 17000000;      // 0.1M

  const int* dsrc = dei;
  const int* ddst = dei + EDU;
  const int* esrc = ei;
  const int* edst = ei + EP;

  const int gE1 = (EP + NP + TPB - 1)/TPB;   // primal edges incl. self loops

  // ---- dual GCN branch ----
  hipMemsetAsync(dinv, 0, (size_t)NDU*sizeof(float), stream);
  k_deg   <<<EDU/TPB, TPB, 0, stream>>>(ddst, dinv);
  k_dinv  <<<NDU/TPB, TPB, 0, stream>>>(dinv);
  k_dh1   <<<NDU/TPB, TPB, 0, stream>>>(dx, Wg1, dinv, A);
  hipMemsetAsync(B, 0, (size_t)NDU*8*sizeof(float), stream);
  k_dscat1<<<EDU/TPB, TPB, 0, stream>>>(dsrc, ddst, A, B);
  k_q1fin <<<NDU/TPB, TPB, 0, stream>>>(A, B, dinv, bg1);
  k_dh2   <<<NDU/TPB, TPB, 0, stream>>>(B, Wg2, dinv, A);
  hipMemsetAsync(Qo, 0, (size_t)NDU*16*sizeof(float), stream);
  k_dscat2<<<EDU/TPB, TPB, 0, stream>>>(dsrc, ddst, A, Qo);
  k_qfin  <<<NDU/TPB, TPB, 0, stream>>>(A, Qo, dinv, bg2);

  // ---- primal GAT branch ----
  k_gemm1 <<<NP/16, TPB, 0, stream>>>(x, W1, H1);
  k_alpha <<<NP*NHEAD/TPB, TPB, 0, stream>>>(H1, aw1s, aw1d, als, ald);
  hipMemsetAsync(den1, 0, (size_t)NP*NHEAD*sizeof(float), stream);
  k_den1  <<<gE1, TPB, 0, stream>>>(esrc, edst, als, ald, den1);
  hipMemsetAsync(O1, 0, (size_t)NP*64*sizeof(float), stream);
  k_agg1  <<<gE1, TPB, 0, stream>>>(esrc, edst, als, ald, den1, H1, O1);
  k_elu   <<<NP*64/TPB, TPB, 0, stream>>>(O1, b1);
  k_g     <<<(NP+TPB-1)/TPB, TPB, 0, stream>>>(O1, W2, aw2s, aw2d, G, as2, ad2);
  hipMemsetAsync(den2, 0, (size_t)NP*sizeof(float), stream);
  k_den2  <<<gE1, TPB, 0, stream>>>(esrc, edst, as2, ad2, den2);
  k_outinit<<<NP*16/TPB, TPB, 0, stream>>>(out, b2);
  k_agg2  <<<gE1, TPB, 0, stream>>>(esrc, edst, as2, ad2, den2, G, out);
}

// Round 2
// 1883.691 us; speedup vs baseline: 6.7260x; 6.7260x over previous
//
#include <hip/hip_runtime.h>
#include <math.h>

// Problem constants (fixed by the reference)
#define NP    100000      // primal nodes
#define EP    1600000     // primal edges
#define NDU   1600000     // dual nodes
#define EDU   3200000     // dual edges
#define FIN   512
#define NHEAD 8
#define HIDC  8
#define NCLS  16
#define NEGS  0.2f
#define TPB   256

static __device__ __forceinline__ float lrelu(float x){ return x > 0.f ? x : NEGS*x; }

// ===================== CSR build (per-dst) =====================
// hist -> 3-kernel exclusive scan -> fill (mutates offs so offs[d] ends at
// segment end; gather uses beg = d? offs[d-1]:0, end = offs[d]).

__global__ void k_hist(const int* __restrict__ dst, int* __restrict__ deg, int n){
  int e = blockIdx.x*TPB + threadIdx.x;
  if(e < n) atomicAdd(deg + dst[e], 1);
}

// block = 256 threads x 8 elems = 2048
__global__ void k_scan1(const int* __restrict__ deg, int* __restrict__ offs,
                        int* __restrict__ bsum, int n){
  __shared__ int lds[TPB];
  const int tid = threadIdx.x;
  const int base = blockIdx.x*2048 + tid*8;
  int ex[8]; int s = 0;
  #pragma unroll
  for(int i=0;i<8;i++){ int idx=base+i; int x = (idx<n)? deg[idx] : 0; ex[i]=s; s+=x; }
  lds[tid] = s; __syncthreads();
  for(int off=1; off<TPB; off<<=1){
    int t = (tid>=off)? lds[tid-off] : 0;
    __syncthreads(); lds[tid] += t; __syncthreads();
  }
  int thrExcl = lds[tid] - s;
  if(tid == TPB-1) bsum[blockIdx.x] = lds[TPB-1];
  #pragma unroll
  for(int i=0;i<8;i++){ int idx=base+i; if(idx<n) offs[idx] = thrExcl + ex[i]; }
}

// single block, up to 1024 block sums, exclusive in place
__global__ void k_scan2(int* __restrict__ bs, int nb){
  __shared__ int lds[TPB];
  const int tid = threadIdx.x;
  int v[4]; int s = 0;
  #pragma unroll
  for(int i=0;i<4;i++){ int idx=tid*4+i; int x = (idx<nb)? bs[idx] : 0; v[i]=s; s+=x; }
  lds[tid] = s; __syncthreads();
  for(int off=1; off<TPB; off<<=1){
    int t = (tid>=off)? lds[tid-off] : 0;
    __syncthreads(); lds[tid] += t; __syncthreads();
  }
  int thrExcl = lds[tid] - s;
  #pragma unroll
  for(int i=0;i<4;i++){ int idx=tid*4+i; if(idx<nb) bs[idx] = thrExcl + v[i]; }
}

__global__ void k_scan3(int* __restrict__ offs, const int* __restrict__ bs, int n){
  int i = blockIdx.x*TPB + threadIdx.x;
  if(i < n) offs[i] += bs[i>>11];
}

__global__ void k_fill(const int* __restrict__ src, const int* __restrict__ dst,
                       int* __restrict__ offs, int* __restrict__ col, int n){
  int e = blockIdx.x*TPB + threadIdx.x;
  if(e >= n) return;
  int pos = atomicAdd(offs + dst[e], 1);
  col[pos] = src[e];
}

// dinv[i] = rsqrt(deg+1), written in place over the int deg array
__global__ void k_dinv(int* __restrict__ degio, int n){
  int i = blockIdx.x*TPB + threadIdx.x;
  if(i >= n) return;
  int d = degio[i];
  ((float*)degio)[i] = rsqrtf((float)d + 1.0f);
}

// ===================== dual (line-graph) GCN branch =====================
// Layer 1 fused gather: Q1[d][c] = relu(dinv[d]*( sum_{s in N(d)} g(s,c) + g(d,c) ) + bg1[c])
// with g(n,c) = dinv[n] * sum_k dx[n][k]*Wg1[k][c]   (h1 never materialized)
__global__ void k_dgath1(const float* __restrict__ dx, const float* __restrict__ Wg1,
                         const float* __restrict__ bg1, const float* __restrict__ dinv,
                         const int* __restrict__ offs, const int* __restrict__ col,
                         float* __restrict__ Q1){
  int t = blockIdx.x*TPB + threadIdx.x;   // over NDU*8
  if(t >= NDU*8) return;
  int d = t >> 3, c = t & 7;
  const float w0 = Wg1[c], w1 = Wg1[8+c], w2 = Wg1[16+c], w3 = Wg1[24+c];
  int beg = d ? offs[d-1] : 0;
  int end = offs[d];
  const float4 xd = *(const float4*)(dx + d*4);
  float acc = dinv[d]*(xd.x*w0 + xd.y*w1 + xd.z*w2 + xd.w*w3);  // self loop
  for(int j=beg; j<end; j++){
    int s = col[j];
    const float4 xs = *(const float4*)(dx + s*4);
    acc += dinv[s]*(xs.x*w0 + xs.y*w1 + xs.z*w2 + xs.w*w3);
  }
  float v = dinv[d]*acc + bg1[c];
  Q1[t] = v > 0.f ? v : 0.f;
}

// Layer 2 fused gather: Qo[d][c] = dinv[d]*( sum g2(s,c) + g2(d,c) ) + bg2[c]
// with g2(n,c) = dinv[n]*sum_k Q1[n][k]*Wg2[k][c]
__global__ void k_dgath2(const float* __restrict__ Q1, const float* __restrict__ Wg2,
                         const float* __restrict__ bg2, const float* __restrict__ dinv,
                         const int* __restrict__ offs, const int* __restrict__ col,
                         float* __restrict__ Qo){
  int t = blockIdx.x*TPB + threadIdx.x;   // over NDU*16
  if(t >= NDU*16) return;
  int d = t >> 4, c = t & 15;
  float w[8];
  #pragma unroll
  for(int k=0;k<8;k++) w[k] = Wg2[k*16+c];
  int beg = d ? offs[d-1] : 0;
  int end = offs[d];
  float acc;
  {
    float g = 0.f;
    #pragma unroll
    for(int k=0;k<8;k++) g += Q1[d*8+k]*w[k];
    acc = dinv[d]*g;                      // self loop
  }
  for(int j=beg; j<end; j++){
    int s = col[j];
    float g = 0.f;
    #pragma unroll
    for(int k=0;k<8;k++) g += Q1[s*8+k]*w[k];
    acc += dinv[s]*g;
  }
  Qo[t] = dinv[d]*acc + bg2[c];
}

// ===================== primal GAT branch =====================

// H = x @ W1 : [100000,512]x[512,64]. 16 rows/block staged in LDS.
__global__ __launch_bounds__(TPB) void k_gemm1(const float* __restrict__ x,
                                               const float* __restrict__ W,
                                               float* __restrict__ H){
  __shared__ float xs[16][FIN+4];
  const int r0 = blockIdx.x*16;
  for(int i=threadIdx.x; i<16*(FIN/4); i+=TPB){
    int r = i >> 7;
    int k4 = (i & 127)*4;
    float4 v = *(const float4*)(x + (r0+r)*FIN + k4);
    xs[r][k4+0]=v.x; xs[r][k4+1]=v.y; xs[r][k4+2]=v.z; xs[r][k4+3]=v.w;
  }
  __syncthreads();
  const int c4 = (threadIdx.x & 15)*4;
  const int rq = threadIdx.x >> 4;
  float a0=0.f,a1=0.f,a2=0.f,a3=0.f;
  #pragma unroll 8
  for(int k=0;k<FIN;k++){
    float xv = xs[rq][k];
    float4 wv = *(const float4*)(W + k*64 + c4);
    a0 += xv*wv.x; a1 += xv*wv.y; a2 += xv*wv.z; a3 += xv*wv.w;
  }
  *(float4*)(H + (r0+rq)*64 + c4) = make_float4(a0,a1,a2,a3);
}

__global__ void k_alpha(const float* __restrict__ H, const float* __restrict__ aw_s,
                        const float* __restrict__ aw_d,
                        float* __restrict__ als, float* __restrict__ ald){
  int i = blockIdx.x*TPB + threadIdx.x;     // over NP*8
  if(i >= NP*NHEAD) return;
  int n = i >> 3, h = i & 7;
  const float* hp = H + n*64 + h*8;
  float s = 0.f, d = 0.f;
  #pragma unroll
  for(int c=0;c<8;c++){ float v = hp[c]; s += v*aw_s[h*8+c]; d += v*aw_d[h*8+c]; }
  als[i] = s; ald[i] = d;
}

// GAT layer-1 gather: one wave per dst node; in-wave softmax (no segment_max:
// |logit| <~ 6 so exp() is fp32-safe and softmax is shift-invariant).
// Phase 1: 8 edges x 8 heads per iter -> den[h]. Phase 2: 64 lanes = channels.
// Fused: + b1, ELU.
__global__ __launch_bounds__(TPB) void k_agg1(const int* __restrict__ offs,
                                              const int* __restrict__ col,
                                              const float* __restrict__ als,
                                              const float* __restrict__ ald,
                                              const float* __restrict__ H,
                                              const float* __restrict__ b1,
                                              float* __restrict__ O){
  int d = (blockIdx.x*TPB + threadIdx.x) >> 6;   // wave per dst; grid covers NP exactly
  int lane = threadIdx.x & 63;
  int beg = d ? offs[d-1] : 0;
  int end = offs[d];
  // phase 1: denominator per head
  int h1 = lane & 7;
  float aldv = ald[d*8 + h1];
  float den = 0.f;
  for(int j0=beg; j0<end; j0+=8){
    int j = j0 + (lane>>3);
    if(j < end){
      int s = col[j];
      den += __expf(lrelu(als[s*8 + h1] + aldv));
    }
  }
  den += __shfl_xor(den, 8);
  den += __shfl_xor(den, 16);
  den += __shfl_xor(den, 32);
  den += __expf(lrelu(als[d*8 + h1] + aldv));      // self loop
  // phase 2: lane = output channel, head = lane>>3
  int hc = lane >> 3;
  float denc = __shfl(den, hc);     // lane hc holds den for head hc
  float aldc = __shfl(aldv, hc);
  float inv = 1.f / (denc + 1e-16f);
  float acc = 0.f;
  for(int j=beg; j<end; j++){
    int s = col[j];
    float w = __expf(lrelu(als[s*8 + hc] + aldc)) * inv;
    acc += w * H[s*64 + lane];
  }
  float ws = __expf(lrelu(als[d*8 + hc] + aldc)) * inv;
  acc += ws * H[d*64 + lane];
  float v = acc + b1[lane];
  O[d*64 + lane] = v > 0.f ? v : expm1f(v);        // ELU fused
}

// G = O @ W2 ([64][16]) + layer-2 attention logits (heads=1)
__global__ void k_g(const float* __restrict__ O, const float* __restrict__ W2,
                    const float* __restrict__ asw, const float* __restrict__ adw,
                    float* __restrict__ G, float* __restrict__ as2, float* __restrict__ ad2){
  __shared__ float w2s[64*NCLS];
  for(int i=threadIdx.x; i<64*NCLS; i+=TPB) w2s[i] = W2[i];
  __syncthreads();
  int n = blockIdx.x*TPB + threadIdx.x;
  if(n >= NP) return;
  float g[16];
  #pragma unroll
  for(int c=0;c<16;c++) g[c] = 0.f;
  const float* op = O + n*64;
  #pragma unroll
  for(int k4=0;k4<64;k4+=4){
    float4 v = *(const float4*)(op + k4);
    #pragma unroll
    for(int c=0;c<16;c++){
      g[c] += v.x*w2s[(k4+0)*16+c] + v.y*w2s[(k4+1)*16+c]
            + v.z*w2s[(k4+2)*16+c] + v.w*w2s[(k4+3)*16+c];
    }
  }
  float s=0.f, t=0.f;
  #pragma unroll
  for(int c=0;c<16;c++){ s += g[c]*asw[c]; t += g[c]*adw[c]; }
  #pragma unroll
  for(int c4=0;c4<16;c4+=4)
    *(float4*)(G + n*16 + c4) = make_float4(g[c4],g[c4+1],g[c4+2],g[c4+3]);
  as2[n] = s; ad2[n] = t;
}

// GAT layer-2 gather: one wave per dst. Phase 1: 64 edges/iter -> den.
// Phase 2: 4 edges x 16 channels. Fused + b2 -> final output.
__global__ __launch_bounds__(TPB) void k_agg2(const int* __restrict__ offs,
                                              const int* __restrict__ col,
                                              const float* __restrict__ as2,
                                              const float* __restrict__ ad2,
                                              const float* __restrict__ G,
                                              const float* __restrict__ b2,
                                              float* __restrict__ out){
  int d = (blockIdx.x*TPB + threadIdx.x) >> 6;
  int lane = threadIdx.x & 63;
  int beg = d ? offs[d-1] : 0;
  int end = offs[d];
  float ad2d = ad2[d];
  float den = 0.f;
  for(int j0=beg; j0<end; j0+=64){
    int j = j0 + lane;
    if(j < end) den += __expf(lrelu(as2[col[j]] + ad2d));
  }
  #pragma unroll
  for(int off=32; off; off>>=1) den += __shfl_xor(den, off);
  den += __expf(lrelu(as2[d] + ad2d));             // self loop
  float inv = 1.f / (den + 1e-16f);
  int c = lane & 15, slot = lane >> 4;
  float acc = 0.f;
  for(int j0=beg; j0<end; j0+=4){
    int j = j0 + slot;
    if(j < end){
      int s = col[j];
      acc += __expf(lrelu(as2[s] + ad2d)) * inv * G[s*16 + c];
    }
  }
  acc += __shfl_xor(acc, 16);
  acc += __shfl_xor(acc, 32);
  acc += __expf(lrelu(as2[d] + ad2d)) * inv * G[d*16 + c];   // self loop
  if(lane < 16) out[d*16 + c] = acc + b2[c];
}

// ===================== launch =====================

extern "C" void kernel_launch(void* const* d_in, const int* in_sizes, int n_in,
                              void* d_out, int out_size, void* d_ws, size_t ws_size,
                              hipStream_t stream){
  const float* x    = (const float*)d_in[0];
  const int*   ei   = (const int*)  d_in[1];
  const float* dx   = (const float*)d_in[2];
  const int*   dei  = (const int*)  d_in[3];
  const float* W1   = (const float*)d_in[4];
  const float* aw1s = (const float*)d_in[5];
  const float* aw1d = (const float*)d_in[6];
  const float* b1   = (const float*)d_in[7];
  const float* W2   = (const float*)d_in[8];
  const float* aw2s = (const float*)d_in[9];
  const float* aw2d = (const float*)d_in[10];
  const float* b2   = (const float*)d_in[11];
  const float* Wg1  = (const float*)d_in[12];
  const float* bg1  = (const float*)d_in[13];
  const float* Wg2  = (const float*)d_in[14];
  const float* bg2  = (const float*)d_in[15];

  float* out = (float*)d_out;          // [NP,16]
  float* Qo  = out + NP*NCLS;          // [NDU,16]

  // workspace layout (4B words), total ~32M words = 128 MB:
  //   R[25.6M]  -- dual: Q1 (12.8M); primal: H1|O1|G|als|ald|as2|ad2|offsP|colP
  //   dinv/degD[1.6M] | offsD[1.6M] | colD[3.2M] | bsum[1024]
  float* R     = (float*)d_ws;
  int*   degD  = (int*)(R + 25600000);      // becomes float dinv in place
  int*   offsD = degD + 1600000;
  int*   colD  = offsD + 1600000;
  int*   bsum  = colD + 3200000;            // 1024
  float* dinvF = (float*)degD;

  // dual-phase overlay
  float* Q1   = R;                    // 12.8M
  // primal-phase overlay (dual branch fully finished before primal gathers)
  float* H1   = R;                    // 6.4M
  float* O1   = R + 6400000;          // 6.4M
  float* G    = R + 12800000;         // 1.6M
  float* als  = R + 14400000;         // 0.8M
  float* ald  = R + 15200000;         // 0.8M
  float* as2  = R + 16000000;         // 0.1M
  float* ad2  = R + 16100000;         // 0.1M
  int*   degP = (int*)(R + 16200000); // 0.1M
  int*   offsP= degP + 100000;        // 0.1M
  int*   colP = offsP + 100000;       // 1.6M

  const int* dsrc = dei;
  const int* ddst = dei + EDU;
  const int* esrc = ei;
  const int* edst = ei + EP;

  // ---- dual CSR build ----
  hipMemsetAsync(degD, 0, (size_t)NDU*sizeof(int), stream);
  k_hist <<<EDU/TPB, TPB, 0, stream>>>(ddst, degD, EDU);
  k_scan1<<<(NDU+2047)/2048, TPB, 0, stream>>>(degD, offsD, bsum, NDU);
  k_scan2<<<1, TPB, 0, stream>>>(bsum, (NDU+2047)/2048);
  k_scan3<<<NDU/TPB, TPB, 0, stream>>>(offsD, bsum, NDU);
  k_dinv <<<NDU/TPB, TPB, 0, stream>>>(degD, NDU);            // degD -> dinv (float, in place)
  k_fill <<<EDU/TPB, TPB, 0, stream>>>(dsrc, ddst, offsD, colD, EDU);

  // ---- dual GCN (fused gathers, weights applied on the fly) ----
  k_dgath1<<<NDU*8/TPB,  TPB, 0, stream>>>(dx, Wg1, bg1, dinvF, offsD, colD, Q1);
  k_dgath2<<<NDU*16/TPB, TPB, 0, stream>>>(Q1, Wg2, bg2, dinvF, offsD, colD, Qo);

  // ---- primal CSR build ----
  hipMemsetAsync(degP, 0, (size_t)NP*sizeof(int), stream);
  k_hist <<<EP/TPB, TPB, 0, stream>>>(edst, degP, EP);
  k_scan1<<<(NP+2047)/2048, TPB, 0, stream>>>(degP, offsP, bsum, NP);
  k_scan2<<<1, TPB, 0, stream>>>(bsum, (NP+2047)/2048);
  k_scan3<<<(NP+TPB-1)/TPB, TPB, 0, stream>>>(offsP, bsum, NP);
  k_fill <<<EP/TPB, TPB, 0, stream>>>(esrc, edst, offsP, colP, EP);

  // ---- primal GAT ----
  k_gemm1<<<NP/16, TPB, 0, stream>>>(x, W1, H1);
  k_alpha<<<NP*NHEAD/TPB, TPB, 0, stream>>>(H1, aw1s, aw1d, als, ald);
  k_agg1 <<<NP/4, TPB, 0, stream>>>(offsP, colP, als, ald, H1, b1, O1);
  k_g    <<<(NP+TPB-1)/TPB, TPB, 0, stream>>>(O1, W2, aw2s, aw2d, G, as2, ad2);
  k_agg2 <<<NP/4, TPB, 0, stream>>>(offsP, colP, as2, ad2, G, b2, out);
}